// Round 12
// baseline (57.087 us; speedup 1.0000x reference)
//
#include <hip/hip_runtime.h>

#define S_DIM  2048
#define B_DIM  1024
#define SC_DIM 4096

typedef __bf16 bf16x8 __attribute__((ext_vector_type(8)));
typedef float  f32x4  __attribute__((ext_vector_type(4)));
typedef unsigned short u16x8 __attribute__((ext_vector_type(8)));

__device__ __forceinline__ unsigned short f2bf(float f) {
    unsigned int u = __builtin_bit_cast(unsigned int, f);
    return (unsigned short)((u + 0x7FFFu + ((u >> 16) & 1u)) >> 16);
}

// ---------------- fused prepack: BOTH operands in MFMA-frag order ----------------
// frag layout: ws[((grp*32 + kb)*64 + lane)*8 + j] = val[idx = grp*16 + (lane&15)][k = kb*32 + (lane>>4)*8 + j]
// A: idx = shop-row (2048 rows -> 128 groups); B: idx = sc-col (4096 cols -> 256 groups)
__global__ __launch_bounds__(256)
void prepack_ab(const float* __restrict__ proba,
                const float* __restrict__ avail,
                const float* __restrict__ alloc,
                const float* __restrict__ bsc,
                unsigned short* __restrict__ wsA,
                unsigned short* __restrict__ wsB)
{
    __shared__ float lds[64][129];
    const int t = threadIdx.x;

    if (blockIdx.x < 1024) {
        // ---- A: frag-packed bf16(proba * cm), fully coalesced both sides ----
        int c = blockIdx.x * 256 + t;        // 0 .. 262143
        int lane = c & 63;
        int slot = c >> 6;                   // mg*32 + kb
        int mg = slot >> 5;
        int kb = slot & 31;
        int row = mg * 16 + (lane & 15);
        int k   = kb * 32 + (lane >> 4) * 8;

        f32x4 p0 = *(const f32x4*)&proba[(size_t)row * B_DIM + k];
        f32x4 p1 = *(const f32x4*)&proba[(size_t)row * B_DIM + k + 4];
        f32x4 av0 = *(const f32x4*)&avail[k];
        f32x4 av1 = *(const f32x4*)&avail[k + 4];
        f32x4 al0 = *(const f32x4*)&alloc[k];
        f32x4 al1 = *(const f32x4*)&alloc[k + 4];

        u16x8 w;
        #pragma unroll
        for (int i = 0; i < 4; ++i) {
            float pv = p0[i];
            bool oa = (av0[i] - pv < 0.f) && (pv > 0.f);
            bool ob = (al0[i] + pv < 0.f) && (pv < 0.f);
            w[i] = f2bf(pv * ((oa || ob) ? 0.01f : 1.0f));
        }
        #pragma unroll
        for (int i = 0; i < 4; ++i) {
            float pv = p1[i];
            bool oa = (av1[i] - pv < 0.f) && (pv > 0.f);
            bool ob = (al1[i] + pv < 0.f) && (pv < 0.f);
            w[4 + i] = f2bf(pv * ((oa || ob) ? 0.01f : 1.0f));
        }
        *(u16x8*)&wsA[(size_t)c * 8] = w;
    } else {
        // ---- B: transpose 64k x 128n tile via LDS, write frag-packed ----
        int b2 = blockIdx.x - 1024;           // 0..511
        const int bn0 = (b2 & 31) * 128;      // col span
        const int k0  = (b2 >> 5) * 64;       // k span

        #pragma unroll
        for (int p = 0; p < 8; ++p) {
            int kl = (t >> 5) + p * 8;
            int cl = (t & 31) * 4;
            f32x4 v = *(const f32x4*)&bsc[(size_t)(k0 + kl) * SC_DIM + bn0 + cl];
            lds[kl][cl]     = v[0];
            lds[kl][cl + 1] = v[1];
            lds[kl][cl + 2] = v[2];
            lds[kl][cl + 3] = v[3];
        }
        __syncthreads();

        // 16 frags (8 n-groups x 2 kb); 4 thread-groups of 64 lanes, 4 frags each
        const int g    = t >> 6;              // 0..3
        const int lane = t & 63;
        #pragma unroll
        for (int q = 0; q < 4; ++q) {
            int f   = g * 4 + q;              // 0..15
            int ngl = f >> 1;                 // 0..7
            int kbl = f & 1;                  // 0..1
            int nl  = ngl * 16 + (lane & 15);
            int kl  = kbl * 32 + (lane >> 4) * 8;
            u16x8 w;
            #pragma unroll
            for (int i = 0; i < 8; ++i)
                w[i] = f2bf(lds[kl + i][nl]);
            size_t slot = ((size_t)(bn0 / 16 + ngl) * 32 + (k0 / 32 + kbl)) * 64 + lane;
            *(u16x8*)&wsB[slot * 8] = w;
        }
    }
}

// ---------------- main GEMM: no LDS, no barriers — frag regs straight from L2 ----------------
__global__ __launch_bounds__(256, 2)
void gemm_rf(const unsigned short* __restrict__ wsA,
             const unsigned short* __restrict__ wsB,
             const float* __restrict__ cur,
             float* __restrict__ out)
{
    const int tid  = threadIdx.x;
    const int lane = tid & 63;
    const int wid  = tid >> 6;
    const int wm   = wid >> 1;
    const int wn   = wid & 1;
    const int l16  = lane & 15;
    const int lg   = lane >> 4;

    // XCD ownership: XCD x owns n-tiles [4x,4x+4) (1MB B slice L2-resident; A 4MB L2-resident)
    const int bid    = blockIdx.x;
    const int x      = bid & 7;
    const int l      = bid >> 3;
    const int n_tile = x * 4 + (l & 3);
    const int m_tile = l >> 2;
    const int row0   = m_tile * 128 + wm * 64;
    const int col0   = n_tile * 128 + wn * 64;

    const unsigned short* aBase = wsA + ((size_t)(row0 >> 4) * 32 * 64 + lane) * 8;
    const unsigned short* bBase = wsB + ((size_t)(col0 >> 4) * 32 * 64 + lane) * 8;

    f32x4 acc[4][4];
    #pragma unroll
    for (int i = 0; i < 4; ++i)
        #pragma unroll
        for (int j = 0; j < 4; ++j)
            acc[i][j] = {0.f, 0.f, 0.f, 0.f};

    // frag (f, kb) at base + (f*32 + kb)*512 elems (1 KB contiguous, coalesced dwordx4)
    auto loadset = [&](int t, bf16x8 (&a)[2][4], bf16x8 (&b)[2][4]) {
        #pragma unroll
        for (int kk = 0; kk < 2; ++kk) {
            #pragma unroll
            for (int f = 0; f < 4; ++f) {
                a[kk][f] = *(const bf16x8*)(aBase + (size_t)(f * 32 + 2 * t + kk) * 512);
                b[kk][f] = *(const bf16x8*)(bBase + (size_t)(f * 32 + 2 * t + kk) * 512);
            }
        }
    };

    bf16x8 aP[2][4], bP[2][4], aQ[2][4], bQ[2][4];
    float cpre[2][4];

    loadset(0, aP, bP);

    auto body = [&](int t, bf16x8 (&aC)[2][4], bf16x8 (&bC)[2][4],
                    bf16x8 (&aN)[2][4], bf16x8 (&bN)[2][4]) {
        // fold cur slots loaded at t-1 (before cpre overwrite; register anti-dep keeps order)
        if (t >= 8) {
            #pragma unroll
            for (int u = 0; u < 2; ++u) {
                const int s  = 2 * (t - 8) + u;
                const int mf = s >> 2, nf = s & 3;
                #pragma unroll
                for (int j = 0; j < 4; ++j)
                    acc[mf][nf][j] += cpre[u][j];
            }
        }

        if (t < 15)
            loadset(t + 1, aN, bN);          // prefetch next K-step (flies under MFMAs)

        if (t >= 7 && t < 15) {             // 2 cur slots prefetched per iter
            #pragma unroll
            for (int u = 0; u < 2; ++u) {
                const int s   = 2 * (t - 7) + u;
                const int mf  = s >> 2, nf = s & 3;
                const int row = row0 + mf * 16 + lg * 4;
                const int col = col0 + nf * 16 + l16;
                #pragma unroll
                for (int j = 0; j < 4; ++j)
                    cpre[u][j] = cur[(size_t)(row + j) * SC_DIM + col];
            }
        }

        #pragma unroll
        for (int kk = 0; kk < 2; ++kk)
            #pragma unroll
            for (int mf = 0; mf < 4; ++mf)
                #pragma unroll
                for (int nf = 0; nf < 4; ++nf)
                    acc[mf][nf] = __builtin_amdgcn_mfma_f32_16x16x32_bf16(
                        aC[kk][mf], bC[kk][nf], acc[mf][nf], 0, 0, 0);
    };

    #pragma unroll
    for (int tt = 0; tt < 8; ++tt) {         // 16 K-steps, static P/Q register roles
        body(2 * tt,     aP, bP, aQ, bQ);
        body(2 * tt + 1, aQ, bQ, aP, bP);
    }

    // store-only epilogue (cur fully folded in-loop)
    #pragma unroll
    for (int mf = 0; mf < 4; ++mf)
        #pragma unroll
        for (int j = 0; j < 4; ++j)
            #pragma unroll
            for (int nf = 0; nf < 4; ++nf) {
                int row = row0 + mf * 16 + lg * 4 + j;
                int col = col0 + nf * 16 + l16;
                out[(size_t)row * SC_DIM + col] = acc[mf][nf][j];
            }
}

// ---------------- fallback (fused single-pass), used only if ws too small ----------------
#define FBM 128
#define FBN 128
#define LDK 72
__global__ __launch_bounds__(256, 2)
void opt_gemm_fused(const float* __restrict__ proba,
                    const float* __restrict__ cur,
                    const float* __restrict__ bsc,
                    const float* __restrict__ avail,
                    const float* __restrict__ alloc,
                    float* __restrict__ out)
{
    __shared__ __align__(16) unsigned short sA[FBM * LDK];
    __shared__ __align__(16) unsigned short sB[FBN * LDK];
    const int tid = threadIdx.x;
    const int lane = tid & 63;
    const int wid = tid >> 6;
    const int wm = wid >> 1, wn = wid & 1;
    const int bm0 = blockIdx.y * FBM, bn0 = blockIdx.x * FBN;
    const int af4 = tid & 15, ar0 = tid >> 4;
    const int bnn = tid & 127, bkh = tid >> 7;
    const int l16 = lane & 15, lg = lane >> 4;

    f32x4 acc[4][4];
    #pragma unroll
    for (int i = 0; i < 4; ++i)
        #pragma unroll
        for (int j = 0; j < 4; ++j) acc[i][j] = {0.f, 0.f, 0.f, 0.f};

    for (int k0 = 0; k0 < B_DIM; k0 += 64) {
        f32x4 av = *(const f32x4*)&avail[k0 + af4 * 4];
        f32x4 al = *(const f32x4*)&alloc[k0 + af4 * 4];
        #pragma unroll
        for (int pass = 0; pass < 8; ++pass) {
            int r = ar0 + pass * 16;
            f32x4 p = *(const f32x4*)&proba[(size_t)(bm0 + r) * B_DIM + k0 + af4 * 4];
            unsigned short w[4];
            #pragma unroll
            for (int i = 0; i < 4; ++i) {
                float pv = p[i];
                bool oa = (av[i] - pv < 0.f) && (pv > 0.f);
                bool ob = (al[i] + pv < 0.f) && (pv < 0.f);
                w[i] = f2bf(pv * ((oa || ob) ? 0.01f : 1.0f));
            }
            sA[r * LDK + af4 * 4 + 0] = w[0];
            sA[r * LDK + af4 * 4 + 1] = w[1];
            sA[r * LDK + af4 * 4 + 2] = w[2];
            sA[r * LDK + af4 * 4 + 3] = w[3];
        }
        #pragma unroll
        for (int g = 0; g < 4; ++g) {
            u16x8 w;
            #pragma unroll
            for (int i = 0; i < 8; ++i) {
                int kk = bkh * 32 + g * 8 + i;
                w[i] = f2bf(bsc[(size_t)(k0 + kk) * SC_DIM + bn0 + bnn]);
            }
            *(u16x8*)&sB[bnn * LDK + bkh * 32 + g * 8] = w;
        }
        __syncthreads();
        #pragma unroll
        for (int kk = 0; kk < 2; ++kk) {
            bf16x8 afr[4], bfr[4];
            #pragma unroll
            for (int mf = 0; mf < 4; ++mf)
                afr[mf] = *(const bf16x8*)&sA[(wm * 64 + mf * 16 + l16) * LDK + kk * 32 + lg * 8];
            #pragma unroll
            for (int nf = 0; nf < 4; ++nf)
                bfr[nf] = *(const bf16x8*)&sB[(wn * 64 + nf * 16 + l16) * LDK + kk * 32 + lg * 8];
            #pragma unroll
            for (int mf = 0; mf < 4; ++mf)
                #pragma unroll
                for (int nf = 0; nf < 4; ++nf)
                    acc[mf][nf] = __builtin_amdgcn_mfma_f32_16x16x32_bf16(
                        afr[mf], bfr[nf], acc[mf][nf], 0, 0, 0);
        }
        __syncthreads();
    }
    #pragma unroll
    for (int mf = 0; mf < 4; ++mf)
        #pragma unroll
        for (int j = 0; j < 4; ++j) {
            int row = bm0 + wm * 64 + mf * 16 + lg * 4 + j;
            #pragma unroll
            for (int nf = 0; nf < 4; ++nf) {
                int col = bn0 + wn * 64 + nf * 16 + l16;
                size_t idx = (size_t)row * SC_DIM + col;
                out[idx] = cur[idx] + acc[mf][nf][j];
            }
        }
}

extern "C" void kernel_launch(void* const* d_in, const int* in_sizes, int n_in,
                              void* d_out, int out_size, void* d_ws, size_t ws_size,
                              hipStream_t stream) {
    const float* proba = (const float*)d_in[0];
    const float* cur   = (const float*)d_in[1];
    const float* bsc   = (const float*)d_in[2];
    const float* avail = (const float*)d_in[3];
    const float* alloc = (const float*)d_in[4];
    float* out = (float*)d_out;

    const size_t wsA_bytes = (size_t)S_DIM * B_DIM * 2;   // 4 MB
    const size_t wsB_bytes = (size_t)SC_DIM * B_DIM * 2;  // 8 MB

    if (ws_size >= wsA_bytes + wsB_bytes) {
        unsigned short* wsA = (unsigned short*)d_ws;
        unsigned short* wsB = (unsigned short*)((char*)d_ws + wsA_bytes);

        prepack_ab<<<dim3(1024 + 512), 256, 0, stream>>>(proba, avail, alloc, bsc, wsA, wsB);
        gemm_rf<<<dim3(512), 256, 0, stream>>>(wsA, wsB, cur, out);
    } else {
        opt_gemm_fused<<<dim3(SC_DIM / FBN, S_DIM / FBM), 256, 0, stream>>>(
            proba, cur, bsc, avail, alloc, out);
    }
}

// Round 13
// 47.380 us; speedup vs baseline: 1.2049x; 1.2049x over previous
//
#include <hip/hip_runtime.h>

#define S_DIM  2048
#define B_DIM  1024
#define SC_DIM 4096

#define BM 128
#define BN 128
#define BK 128

typedef __bf16 bf16x8 __attribute__((ext_vector_type(8)));
typedef float  f32x4  __attribute__((ext_vector_type(4)));
typedef unsigned short u16x8 __attribute__((ext_vector_type(8)));

__device__ __forceinline__ unsigned short f2bf(float f) {
    unsigned int u = __builtin_bit_cast(unsigned int, f);
    return (unsigned short)((u + 0x7FFFu + ((u >> 16) & 1u)) >> 16);
}

__device__ __forceinline__ void gld_lds16(const void* g, void* l) {
    __builtin_amdgcn_global_load_lds(
        (const __attribute__((address_space(1))) unsigned int*)g,
        (__attribute__((address_space(3))) unsigned int*)l, 16, 0, 0);
}

// ---------------- fused prepack (identical to R8/R10) ----------------
// blocks [0,1024):  wsA[n][k] = bf16(proba*cm), 16B-chunk-swizzled (chunk G -> (G&~7)|((G&7)^(n&7)))
// blocks [1024,1536): wsB[n][k] = bf16(bsc[k][n]) transposed, same swizzle
__global__ __launch_bounds__(256)
void prepack_ab(const float* __restrict__ proba,
                const float* __restrict__ avail,
                const float* __restrict__ alloc,
                const float* __restrict__ bsc,
                unsigned short* __restrict__ wsA,
                unsigned short* __restrict__ wsB)
{
    __shared__ float lds[64][129];
    const int t = threadIdx.x;

    if (blockIdx.x < 1024) {
        int c = blockIdx.x * 256 + t;
        int n = c >> 7;
        int G = c & 127;
        int k = G * 8;

        f32x4 p0 = *(const f32x4*)&proba[(size_t)n * B_DIM + k];
        f32x4 p1 = *(const f32x4*)&proba[(size_t)n * B_DIM + k + 4];
        f32x4 av0 = *(const f32x4*)&avail[k];
        f32x4 av1 = *(const f32x4*)&avail[k + 4];
        f32x4 al0 = *(const f32x4*)&alloc[k];
        f32x4 al1 = *(const f32x4*)&alloc[k + 4];

        u16x8 w;
        #pragma unroll
        for (int i = 0; i < 4; ++i) {
            float pv = p0[i];
            bool oa = (av0[i] - pv < 0.f) && (pv > 0.f);
            bool ob = (al0[i] + pv < 0.f) && (pv < 0.f);
            w[i] = f2bf(pv * ((oa || ob) ? 0.01f : 1.0f));
        }
        #pragma unroll
        for (int i = 0; i < 4; ++i) {
            float pv = p1[i];
            bool oa = (av1[i] - pv < 0.f) && (pv > 0.f);
            bool ob = (al1[i] + pv < 0.f) && (pv < 0.f);
            w[4 + i] = f2bf(pv * ((oa || ob) ? 0.01f : 1.0f));
        }
        int Gs = (G & ~7) | ((G & 7) ^ (n & 7));
        *(u16x8*)&wsA[(size_t)n * B_DIM + Gs * 8] = w;
    } else {
        int b2 = blockIdx.x - 1024;
        const int bn0 = (b2 & 31) * 128;
        const int k0  = (b2 >> 5) * 64;

        #pragma unroll
        for (int p = 0; p < 8; ++p) {
            int kl = (t >> 5) + p * 8;
            int cl = (t & 31) * 4;
            f32x4 v = *(const f32x4*)&bsc[(size_t)(k0 + kl) * SC_DIM + bn0 + cl];
            lds[kl][cl]     = v[0];
            lds[kl][cl + 1] = v[1];
            lds[kl][cl + 2] = v[2];
            lds[kl][cl + 3] = v[3];
        }
        __syncthreads();

        #pragma unroll
        for (int p = 0; p < 4; ++p) {
            int g = t & 7;
            int n = (t >> 3) + p * 32;
            u16x8 w;
            #pragma unroll
            for (int i = 0; i < 8; ++i)
                w[i] = f2bf(lds[g * 8 + i][n]);
            int gs = g ^ (n & 7);
            *(u16x8*)&wsB[(size_t)(bn0 + n) * B_DIM + k0 + gs * 8] = w;
        }
    }
}

// ---------------- main GEMM: BK=128, sbuf 64KB, stage-under-MFMA, 8 iters ----------------
__global__ __launch_bounds__(256, 2)
void gemm_pk(const unsigned short* __restrict__ wsA,
             const unsigned short* __restrict__ wsB,
             const float* __restrict__ cur,
             float* __restrict__ out)
{
    __shared__ __align__(16) unsigned short sA[BM * BK];   // 32 KB
    __shared__ __align__(16) unsigned short sB[BN * BK];   // 32 KB

    const int tid  = threadIdx.x;
    const int lane = tid & 63;
    const int wid  = tid >> 6;          // 0..3
    const int wm   = wid >> 1;          // 0..1 : 64-row slice
    const int wn   = wid & 1;           // 0..1 : 64-col slice
    const int l16  = lane & 15;
    const int lg   = lane >> 4;

    // XCD ownership: XCD x owns n-tiles [4x,4x+4) -> per-XCD B slice L2-resident
    const int bid    = blockIdx.x;
    const int x      = bid & 7;
    const int l      = bid >> 3;
    const int n_tile = x * 4 + (l & 3);
    const int m_tile = l >> 2;
    const int bm0    = m_tile * BM;
    const int bn0    = n_tile * BN;

    const int row0 = bm0 + wm * 64;
    const int col0 = bn0 + wn * 64;

    f32x4 acc[4][4];
    #pragma unroll
    for (int i = 0; i < 4; ++i)
        #pragma unroll
        for (int j = 0; j < 4; ++j)
            acc[i][j] = {0.f, 0.f, 0.f, 0.f};

    // staging: 16 chunks of 16B per row (BK=128); c = is*256+tid; row = c>>4; g = c&15
    auto stage = [&](int k0) {
        #pragma unroll
        for (int is = 0; is < 8; ++is) {
            int c = is * 256 + tid;
            int r = c >> 4;
            int g = c & 15;
            gld_lds16(wsA + (size_t)(bm0 + r) * B_DIM + k0 + g * 8, &sA[c * 8]);
        }
        #pragma unroll
        for (int is = 0; is < 8; ++is) {
            int c = is * 256 + tid;
            int r = c >> 4;
            int g = c & 15;
            gld_lds16(wsB + (size_t)(bn0 + r) * B_DIM + k0 + g * 8, &sB[c * 8]);
        }
    };

    stage(0);

    float cpre[4][4];   // 4 slots x 4 rows in flight per iteration

    #pragma unroll
    for (int t = 0; t < 8; ++t) {
        __syncthreads();                 // S1: stage(t) + cur(t-1) landed (vmcnt0)

        // fold cur slots loaded at t-1 (before cpre overwrite later this iter)
        if (t >= 4) {
            #pragma unroll
            for (int u = 0; u < 4; ++u) {
                const int s  = 4 * (t - 4) + u;
                const int mf = s >> 2, nf = s & 3;
                #pragma unroll
                for (int j = 0; j < 4; ++j)
                    acc[mf][nf][j] += cpre[u][j];
            }
        }

        // read ALL 32 fragments for this K-step (swizzled, conflict-free)
        bf16x8 afr[4][4], bfr[4][4];
        #pragma unroll
        for (int kk = 0; kk < 4; ++kk) {
            const int s = kk * 4 + lg;       // k-slice 0..15
            const int sc = (s & ~7);
            const int s7 = (s & 7);
            #pragma unroll
            for (int mf = 0; mf < 4; ++mf) {
                int r = wm * 64 + mf * 16 + l16;
                afr[kk][mf] = *(const bf16x8*)&sA[r * BK + ((sc | (s7 ^ (r & 7))) * 8)];
            }
            #pragma unroll
            for (int nf = 0; nf < 4; ++nf) {
                int r = wn * 64 + nf * 16 + l16;
                bfr[kk][nf] = *(const bf16x8*)&sB[r * BK + ((sc | (s7 ^ (r & 7))) * 8)];
            }
        }
        __syncthreads();                 // S2: all waves done reading, LDS free

        if (t < 7)
            stage((t + 1) * BK);         // 16 gld_lds fly under the 64-MFMA cluster

        if (t >= 3 && t < 7) {           // 4 cur slots (16 loads) under the MFMA cluster
            #pragma unroll
            for (int u = 0; u < 4; ++u) {
                const int s   = 4 * (t - 3) + u;
                const int mf  = s >> 2, nf = s & 3;
                const int row = row0 + mf * 16 + lg * 4;
                const int col = col0 + nf * 16 + l16;
                #pragma unroll
                for (int j = 0; j < 4; ++j)
                    cpre[u][j] = cur[(size_t)(row + j) * SC_DIM + col];
            }
        }
        __builtin_amdgcn_sched_barrier(0);  // keep MFMAs below the load issue

        #pragma unroll
        for (int kk = 0; kk < 4; ++kk)
            #pragma unroll
            for (int mf = 0; mf < 4; ++mf)
                #pragma unroll
                for (int nf = 0; nf < 4; ++nf)
                    acc[mf][nf] = __builtin_amdgcn_mfma_f32_16x16x32_bf16(
                        afr[kk][mf], bfr[kk][nf], acc[mf][nf], 0, 0, 0);
    }

    // store-only epilogue (cur fully folded in-loop)
    #pragma unroll
    for (int mf = 0; mf < 4; ++mf)
        #pragma unroll
        for (int j = 0; j < 4; ++j)
            #pragma unroll
            for (int nf = 0; nf < 4; ++nf) {
                int row = row0 + mf * 16 + lg * 4 + j;
                int col = col0 + nf * 16 + l16;
                out[(size_t)row * SC_DIM + col] = acc[mf][nf][j];
            }
}

// ---------------- fallback (fused single-pass), used only if ws too small ----------------
#define FBM 128
#define FBN 128
#define LDK 72
__global__ __launch_bounds__(256, 2)
void opt_gemm_fused(const float* __restrict__ proba,
                    const float* __restrict__ cur,
                    const float* __restrict__ bsc,
                    const float* __restrict__ avail,
                    const float* __restrict__ alloc,
                    float* __restrict__ out)
{
    __shared__ __align__(16) unsigned short sA[FBM * LDK];
    __shared__ __align__(16) unsigned short sB[FBN * LDK];
    const int tid = threadIdx.x;
    const int lane = tid & 63;
    const int wid = tid >> 6;
    const int wm = wid >> 1, wn = wid & 1;
    const int bm0 = blockIdx.y * FBM, bn0 = blockIdx.x * FBN;
    const int af4 = tid & 15, ar0 = tid >> 4;
    const int bnn = tid & 127, bkh = tid >> 7;
    const int l16 = lane & 15, lg = lane >> 4;

    f32x4 acc[4][4];
    #pragma unroll
    for (int i = 0; i < 4; ++i)
        #pragma unroll
        for (int j = 0; j < 4; ++j) acc[i][j] = {0.f, 0.f, 0.f, 0.f};

    for (int k0 = 0; k0 < B_DIM; k0 += 64) {
        f32x4 av = *(const f32x4*)&avail[k0 + af4 * 4];
        f32x4 al = *(const f32x4*)&alloc[k0 + af4 * 4];
        #pragma unroll
        for (int pass = 0; pass < 8; ++pass) {
            int r = ar0 + pass * 16;
            f32x4 p = *(const f32x4*)&proba[(size_t)(bm0 + r) * B_DIM + k0 + af4 * 4];
            unsigned short w[4];
            #pragma unroll
            for (int i = 0; i < 4; ++i) {
                float pv = p[i];
                bool oa = (av[i] - pv < 0.f) && (pv > 0.f);
                bool ob = (al[i] + pv < 0.f) && (pv < 0.f);
                w[i] = f2bf(pv * ((oa || ob) ? 0.01f : 1.0f));
            }
            sA[r * LDK + af4 * 4 + 0] = w[0];
            sA[r * LDK + af4 * 4 + 1] = w[1];
            sA[r * LDK + af4 * 4 + 2] = w[2];
            sA[r * LDK + af4 * 4 + 3] = w[3];
        }
        #pragma unroll
        for (int g = 0; g < 4; ++g) {
            u16x8 w;
            #pragma unroll
            for (int i = 0; i < 8; ++i) {
                int kk = bkh * 32 + g * 8 + i;
                w[i] = f2bf(bsc[(size_t)(k0 + kk) * SC_DIM + bn0 + bnn]);
            }
            *(u16x8*)&sB[bnn * LDK + bkh * 32 + g * 8] = w;
        }
        __syncthreads();
        #pragma unroll
        for (int kk = 0; kk < 2; ++kk) {
            bf16x8 afr[4], bfr[4];
            #pragma unroll
            for (int mf = 0; mf < 4; ++mf)
                afr[mf] = *(const bf16x8*)&sA[(wm * 64 + mf * 16 + l16) * LDK + kk * 32 + lg * 8];
            #pragma unroll
            for (int nf = 0; nf < 4; ++nf)
                bfr[nf] = *(const bf16x8*)&sB[(wn * 64 + nf * 16 + l16) * LDK + kk * 32 + lg * 8];
            #pragma unroll
            for (int mf = 0; mf < 4; ++mf)
                #pragma unroll
                for (int nf = 0; nf < 4; ++nf)
                    acc[mf][nf] = __builtin_amdgcn_mfma_f32_16x16x32_bf16(
                        afr[mf], bfr[nf], acc[mf][nf], 0, 0, 0);
        }
        __syncthreads();
    }
    #pragma unroll
    for (int mf = 0; mf < 4; ++mf)
        #pragma unroll
        for (int j = 0; j < 4; ++j) {
            int row = bm0 + wm * 64 + mf * 16 + lg * 4 + j;
            #pragma unroll
            for (int nf = 0; nf < 4; ++nf) {
                int col = bn0 + wn * 64 + nf * 16 + l16;
                size_t idx = (size_t)row * SC_DIM + col;
                out[idx] = cur[idx] + acc[mf][nf][j];
            }
        }
}

extern "C" void kernel_launch(void* const* d_in, const int* in_sizes, int n_in,
                              void* d_out, int out_size, void* d_ws, size_t ws_size,
                              hipStream_t stream) {
    const float* proba = (const float*)d_in[0];
    const float* cur   = (const float*)d_in[1];
    const float* bsc   = (const float*)d_in[2];
    const float* avail = (const float*)d_in[3];
    const float* alloc = (const float*)d_in[4];
    float* out = (float*)d_out;

    const size_t wsA_bytes = (size_t)S_DIM * B_DIM * 2;   // 4 MB
    const size_t wsB_bytes = (size_t)SC_DIM * B_DIM * 2;  // 8 MB

    if (ws_size >= wsA_bytes + wsB_bytes) {
        unsigned short* wsA = (unsigned short*)d_ws;
        unsigned short* wsB = (unsigned short*)((char*)d_ws + wsA_bytes);

        prepack_ab<<<dim3(1024 + 512), 256, 0, stream>>>(proba, avail, alloc, bsc, wsA, wsB);
        gemm_pk<<<dim3((S_DIM / BM) * (SC_DIM / BN)), 256, 0, stream>>>(wsA, wsB, cur, out);
    } else {
        opt_gemm_fused<<<dim3(SC_DIM / FBN, S_DIM / FBM), 256, 0, stream>>>(
            proba, cur, bsc, avail, alloc, out);
    }
}

// Round 15
// 39.094 us; speedup vs baseline: 1.4602x; 1.2119x over previous
//
#include <hip/hip_runtime.h>

#define S_DIM  2048
#define B_DIM  1024
#define SC_DIM 4096
#define BK     64

typedef __bf16 bf16x8 __attribute__((ext_vector_type(8)));
typedef float  f32x4  __attribute__((ext_vector_type(4)));
typedef unsigned short u16x8 __attribute__((ext_vector_type(8)));

__device__ __forceinline__ unsigned short f2bf(float f) {
    unsigned int u = __builtin_bit_cast(unsigned int, f);
    return (unsigned short)((u + 0x7FFFu + ((u >> 16) & 1u)) >> 16);
}

__device__ __forceinline__ void gld_lds16(const void* g, void* l) {
    __builtin_amdgcn_global_load_lds(
        (const __attribute__((address_space(1))) unsigned int*)g,
        (__attribute__((address_space(3))) unsigned int*)l, 16, 0, 0);
}

#define VMW0()  asm volatile("s_waitcnt vmcnt(0)"  ::: "memory")
#define VMW8()  asm volatile("s_waitcnt vmcnt(8)"  ::: "memory")
#define VMW16() asm volatile("s_waitcnt vmcnt(16)" ::: "memory")
#define LGKM0() asm volatile("s_waitcnt lgkmcnt(0)" ::: "memory")

// ---------------- fused prepack (identical to R8) ----------------
// blocks [0,1024):  wsA[n][k] = bf16(proba*cm), 16B-chunk-swizzled (chunk G -> (G&~7)|((G&7)^(n&7)))
// blocks [1024,1536): wsB[n][k] = bf16(bsc[k][n]) transposed, same swizzle
__global__ __launch_bounds__(256)
void prepack_ab(const float* __restrict__ proba,
                const float* __restrict__ avail,
                const float* __restrict__ alloc,
                const float* __restrict__ bsc,
                unsigned short* __restrict__ wsA,
                unsigned short* __restrict__ wsB)
{
    __shared__ float lds[64][129];
    const int t = threadIdx.x;

    if (blockIdx.x < 1024) {
        int c = blockIdx.x * 256 + t;
        int n = c >> 7;
        int G = c & 127;
        int k = G * 8;

        f32x4 p0 = *(const f32x4*)&proba[(size_t)n * B_DIM + k];
        f32x4 p1 = *(const f32x4*)&proba[(size_t)n * B_DIM + k + 4];
        f32x4 av0 = *(const f32x4*)&avail[k];
        f32x4 av1 = *(const f32x4*)&avail[k + 4];
        f32x4 al0 = *(const f32x4*)&alloc[k];
        f32x4 al1 = *(const f32x4*)&alloc[k + 4];

        u16x8 w;
        #pragma unroll
        for (int i = 0; i < 4; ++i) {
            float pv = p0[i];
            bool oa = (av0[i] - pv < 0.f) && (pv > 0.f);
            bool ob = (al0[i] + pv < 0.f) && (pv < 0.f);
            w[i] = f2bf(pv * ((oa || ob) ? 0.01f : 1.0f));
        }
        #pragma unroll
        for (int i = 0; i < 4; ++i) {
            float pv = p1[i];
            bool oa = (av1[i] - pv < 0.f) && (pv > 0.f);
            bool ob = (al1[i] + pv < 0.f) && (pv < 0.f);
            w[4 + i] = f2bf(pv * ((oa || ob) ? 0.01f : 1.0f));
        }
        int Gs = (G & ~7) | ((G & 7) ^ (n & 7));
        *(u16x8*)&wsA[(size_t)n * B_DIM + Gs * 8] = w;
    } else {
        int b2 = blockIdx.x - 1024;
        const int bn0 = (b2 & 31) * 128;
        const int k0  = (b2 >> 5) * 64;

        #pragma unroll
        for (int p = 0; p < 8; ++p) {
            int kl = (t >> 5) + p * 8;
            int cl = (t & 31) * 4;
            f32x4 v = *(const f32x4*)&bsc[(size_t)(k0 + kl) * SC_DIM + bn0 + cl];
            lds[kl][cl]     = v[0];
            lds[kl][cl + 1] = v[1];
            lds[kl][cl + 2] = v[2];
            lds[kl][cl + 3] = v[3];
        }
        __syncthreads();

        #pragma unroll
        for (int p = 0; p < 4; ++p) {
            int g = t & 7;
            int n = (t >> 3) + p * 32;
            u16x8 w;
            #pragma unroll
            for (int i = 0; i < 8; ++i)
                w[i] = f2bf(lds[g * 8 + i][n]);
            int gs = g ^ (n & 7);
            *(u16x8*)&wsB[(size_t)(bn0 + n) * B_DIM + k0 + gs * 8] = w;
        }
    }
}

// ---------------- main GEMM: 1 wave = 1 block = one 64x64 tile; NO barriers ----------------
// LDS staging: linear physical chunks (ws already swizzled at prepack);
// ds_read applies the XOR exactly once (rule #21).
__global__ __launch_bounds__(64)
void gemm_w1(const unsigned short* __restrict__ wsA,
             const unsigned short* __restrict__ wsB,
             const float* __restrict__ cur,
             float* __restrict__ out)
{
    __shared__ __align__(16) unsigned short sA[64 * 64];   // 8 KB
    __shared__ __align__(16) unsigned short sB[64 * 64];   // 8 KB

    const int lane = threadIdx.x;       // 0..63
    const int l16  = lane & 15;
    const int lg   = lane >> 4;

    // XCD ownership: XCD x owns n-tiles [8x, 8x+8) -> per-XCD B slice 1 MB (L2-resident)
    const int bid   = blockIdx.x;       // 0..2047
    const int x     = bid & 7;
    const int loc   = bid >> 3;         // 0..255
    const int nt    = x * 8 + (loc & 7);   // 0..63
    const int mt    = loc >> 3;            // 0..31
    const int row0  = mt * 64;
    const int col0  = nt * 64;

    f32x4 acc[4][4];
    #pragma unroll
    for (int i = 0; i < 4; ++i)
        #pragma unroll
        for (int j = 0; j < 4; ++j)
            acc[i][j] = {0.f, 0.f, 0.f, 0.f};

    // stage one 64x64 K-slab of A and B: 8 + 8 gld_lds (1 KB each), LINEAR source
    auto stage = [&](int k0) {
        #pragma unroll
        for (int is = 0; is < 8; ++is) {
            int c = is * 64 + lane;     // chunk 0..511
            int r = c >> 3;             // row 0..63
            int g = c & 7;              // physical 16B chunk in 64-k row
            gld_lds16(wsA + (size_t)(row0 + r) * B_DIM + k0 + g * 8, &sA[c * 8]);
        }
        #pragma unroll
        for (int is = 0; is < 8; ++is) {
            int c = is * 64 + lane;
            int r = c >> 3;
            int g = c & 7;
            gld_lds16(wsB + (size_t)(col0 + r) * B_DIM + k0 + g * 8, &sB[c * 8]);
        }
    };

    stage(0);

    float cpre[2][4];

    #pragma unroll
    for (int t = 0; t < 16; ++t) {
        // retire stage(t) [16 ops]; keep cur(t-1) [8 ops, exists for t in 5..12] in flight
        if (t >= 5 && t <= 12) { VMW8(); } else { VMW0(); }

        // read ALL 16 fragments for this K-step (XOR-swizzled, conflict-free, wave-local)
        bf16x8 afr[2][4], bfr[2][4];
        #pragma unroll
        for (int kk = 0; kk < 2; ++kk) {
            #pragma unroll
            for (int mf = 0; mf < 4; ++mf) {
                int r = mf * 16 + l16;
                afr[kk][mf] = *(const bf16x8*)&sA[r * 64 + (((kk * 4 + lg) ^ (r & 7)) * 8)];
            }
            #pragma unroll
            for (int nf = 0; nf < 4; ++nf) {
                int r = nf * 16 + l16;
                bfr[kk][nf] = *(const bf16x8*)&sB[r * 64 + (((kk * 4 + lg) ^ (r & 7)) * 8)];
            }
        }
        LGKM0();                                   // frags landed in regs; LDS reusable
        __builtin_amdgcn_sched_barrier(0);

        if (t < 15)
            stage((t + 1) * BK);                   // 16 gld_lds fly under the MFMAs
        __builtin_amdgcn_sched_barrier(0);

        // fold cur slots loaded at t-1 (after stage(t+1) issued; wait retires cur only)
        if (t >= 5 && t <= 12) {
            VMW16();                               // cur(t-1) retired; stage(t+1) in flight
            #pragma unroll
            for (int u = 0; u < 2; ++u) {
                const int s  = 2 * (t - 5) + u;
                const int mf = s >> 2, nf = s & 3;
                #pragma unroll
                for (int j = 0; j < 4; ++j)
                    acc[mf][nf][j] += cpre[u][j];
            }
        }

        if (t >= 4 && t <= 11) {                   // issue 2 cur slots (8 loads)
            #pragma unroll
            for (int u = 0; u < 2; ++u) {
                const int s   = 2 * (t - 4) + u;
                const int mf  = s >> 2, nf = s & 3;
                const int row = row0 + mf * 16 + lg * 4;
                const int col = col0 + nf * 16 + l16;
                #pragma unroll
                for (int j = 0; j < 4; ++j)
                    cpre[u][j] = cur[(size_t)(row + j) * SC_DIM + col];
            }
        }
        __builtin_amdgcn_sched_barrier(0);         // keep MFMAs below the load issue

        #pragma unroll
        for (int kk = 0; kk < 2; ++kk)
            #pragma unroll
            for (int mf = 0; mf < 4; ++mf)
                #pragma unroll
                for (int nf = 0; nf < 4; ++nf)
                    acc[mf][nf] = __builtin_amdgcn_mfma_f32_16x16x32_bf16(
                        afr[kk][mf], bfr[kk][nf], acc[mf][nf], 0, 0, 0);
    }

    // store-only epilogue (cur fully folded in-loop)
    #pragma unroll
    for (int mf = 0; mf < 4; ++mf)
        #pragma unroll
        for (int j = 0; j < 4; ++j)
            #pragma unroll
            for (int nf = 0; nf < 4; ++nf) {
                int row = row0 + mf * 16 + lg * 4 + j;
                int col = col0 + nf * 16 + l16;
                out[(size_t)row * SC_DIM + col] = acc[mf][nf][j];
            }
}

// ---------------- fallback (fused single-pass), used only if ws too small ----------------
#define FBM 128
#define FBN 128
#define LDK 72
__global__ __launch_bounds__(256, 2)
void opt_gemm_fused(const float* __restrict__ proba,
                    const float* __restrict__ cur,
                    const float* __restrict__ bsc,
                    const float* __restrict__ avail,
                    const float* __restrict__ alloc,
                    float* __restrict__ out)
{
    __shared__ __align__(16) unsigned short sA[FBM * LDK];
    __shared__ __align__(16) unsigned short sB[FBN * LDK];
    const int tid = threadIdx.x;
    const int lane = tid & 63;
    const int wid = tid >> 6;
    const int wm = wid >> 1, wn = wid & 1;
    const int bm0 = blockIdx.y * FBM, bn0 = blockIdx.x * FBN;
    const int af4 = tid & 15, ar0 = tid >> 4;
    const int bnn = tid & 127, bkh = tid >> 7;
    const int l16 = lane & 15, lg = lane >> 4;

    f32x4 acc[4][4];
    #pragma unroll
    for (int i = 0; i < 4; ++i)
        #pragma unroll
        for (int j = 0; j < 4; ++j) acc[i][j] = {0.f, 0.f, 0.f, 0.f};

    for (int k0 = 0; k0 < B_DIM; k0 += 64) {
        f32x4 av = *(const f32x4*)&avail[k0 + af4 * 4];
        f32x4 al = *(const f32x4*)&alloc[k0 + af4 * 4];
        #pragma unroll
        for (int pass = 0; pass < 8; ++pass) {
            int r = ar0 + pass * 16;
            f32x4 p = *(const f32x4*)&proba[(size_t)(bm0 + r) * B_DIM + k0 + af4 * 4];
            unsigned short w[4];
            #pragma unroll
            for (int i = 0; i < 4; ++i) {
                float pv = p[i];
                bool oa = (av[i] - pv < 0.f) && (pv > 0.f);
                bool ob = (al[i] + pv < 0.f) && (pv < 0.f);
                w[i] = f2bf(pv * ((oa || ob) ? 0.01f : 1.0f));
            }
            sA[r * LDK + af4 * 4 + 0] = w[0];
            sA[r * LDK + af4 * 4 + 1] = w[1];
            sA[r * LDK + af4 * 4 + 2] = w[2];
            sA[r * LDK + af4 * 4 + 3] = w[3];
        }
        #pragma unroll
        for (int g = 0; g < 4; ++g) {
            u16x8 w;
            #pragma unroll
            for (int i = 0; i < 8; ++i) {
                int kk = bkh * 32 + g * 8 + i;
                w[i] = f2bf(bsc[(size_t)(k0 + kk) * SC_DIM + bn0 + bnn]);
            }
            *(u16x8*)&sB[bnn * LDK + bkh * 32 + g * 8] = w;
        }
        __syncthreads();
        #pragma unroll
        for (int kk = 0; kk < 2; ++kk) {
            bf16x8 afr[4], bfr[4];
            #pragma unroll
            for (int mf = 0; mf < 4; ++mf)
                afr[mf] = *(const bf16x8*)&sA[(wm * 64 + mf * 16 + l16) * LDK + kk * 32 + lg * 8];
            #pragma unroll
            for (int nf = 0; nf < 4; ++nf)
                bfr[nf] = *(const bf16x8*)&sB[(wn * 64 + nf * 16 + l16) * LDK + kk * 32 + lg * 8];
            #pragma unroll
            for (int mf = 0; mf < 4; ++mf)
                #pragma unroll
                for (int nf = 0; nf < 4; ++nf)
                    acc[mf][nf] = __builtin_amdgcn_mfma_f32_16x16x32_bf16(
                        afr[mf], bfr[nf], acc[mf][nf], 0, 0, 0);
        }
        __syncthreads();
    }
    #pragma unroll
    for (int mf = 0; mf < 4; ++mf)
        #pragma unroll
        for (int j = 0; j < 4; ++j) {
            int row = bm0 + wm * 64 + mf * 16 + lg * 4 + j;
            #pragma unroll
            for (int nf = 0; nf < 4; ++nf) {
                int col = bn0 + wn * 64 + nf * 16 + l16;
                size_t idx = (size_t)row * SC_DIM + col;
                out[idx] = cur[idx] + acc[mf][nf][j];
            }
        }
}

extern "C" void kernel_launch(void* const* d_in, const int* in_sizes, int n_in,
                              void* d_out, int out_size, void* d_ws, size_t ws_size,
                              hipStream_t stream) {
    const float* proba = (const float*)d_in[0];
    const float* cur   = (const float*)d_in[1];
    const float* bsc   = (const float*)d_in[2];
    const float* avail = (const float*)d_in[3];
    const float* alloc = (const float*)d_in[4];
    float* out = (float*)d_out;

    const size_t wsA_bytes = (size_t)S_DIM * B_DIM * 2;   // 4 MB
    const size_t wsB_bytes = (size_t)SC_DIM * B_DIM * 2;  // 8 MB

    if (ws_size >= wsA_bytes + wsB_bytes) {
        unsigned short* wsA = (unsigned short*)d_ws;
        unsigned short* wsB = (unsigned short*)((char*)d_ws + wsA_bytes);

        prepack_ab<<<dim3(1024 + 512), 256, 0, stream>>>(proba, avail, alloc, bsc, wsA, wsB);
        gemm_w1<<<dim3(2048), 64, 0, stream>>>(wsA, wsB, cur, out);
    } else {
        opt_gemm_fused<<<dim3(SC_DIM / FBN, S_DIM / FBM), 256, 0, stream>>>(
            proba, cur, bsc, avail, alloc, out);
    }
}